// Round 18
// baseline (2596.741 us; speedup 1.0000x reference)
//
#include <hip/hip_runtime.h>
#include <hip/hip_bf16.h>

// RetinaNet head on MI355X. R18 = R15 (best: 1189.7us) with conv_mid's A
// (weights) removed from LDS entirely: A fragments load straight from the
// L2-resident prepped weight tensor into VGPRs (prefetched 1 K-tile ahead,
// 4-way fg line-sharing -> perfectly coalesced), B keeps the R15 LDS ring-3
// path. Per wave/K-tile: LDS reads 7->3, LDS writes 3->1. vmcnt(5) steady
// (prev iter's 4 A-loads + 1 glds are the only allowed in-flight ops;
// cross-iter issue order pinned by barrier + compiler fences).

typedef float  f32x4 __attribute__((ext_vector_type(4)));
typedef int    i32x4 __attribute__((ext_vector_type(4)));
typedef int    i32x2 __attribute__((ext_vector_type(2)));
typedef __bf16 bfrag __attribute__((ext_vector_type(8)));
typedef __bf16 bf4   __attribute__((ext_vector_type(4)));

struct LevelD {
  int H, W, logW, logHW, P, HW, act_off, aoff, blk_start, pos_start;
};
struct Desc  { LevelD lv[6]; };
struct FPtrs { const float* f[6]; };

#define ACT_ELEMS  24735744
#define WREG_OFF   0
#define WCLS_OFF   2359296
#define WREGO_OFF  4718592
#define WCLSO_OFF  4773888
#define ACT0_OFF   4898304
#define ACT1_OFF   29634048
#define ACT2_OFF   54369792
#define WS_ELEMS   54369792ull
#define TOTAL_ANCH 65520
#define CLS_BASE   2096640
#define NPAD_JOBS  9264

__device__ __forceinline__ void glds16(const __bf16* g, __bf16* l) {
  __builtin_amdgcn_global_load_lds(
      (const __attribute__((address_space(1))) void*)g,
      (__attribute__((address_space(3))) void*)l, 16, 0, 0);
}

// bijective XCD-chunk swizzle (m204)
__device__ __forceinline__ int xcd_swz(int b, int nwg) {
  int xcd = b & 7;
  int q = nwg >> 3, r = nwg & 7;
  int base = (xcd < r) ? xcd * (q + 1) : r * (q + 1) + (xcd - r) * q;
  return base + (b >> 3);
}

// ---- halo zeroing ----
__global__ __launch_bounds__(256) void padzero_k(__bf16* __restrict__ act, int nbuf)
{
  static const int kHh[6]   = {32, 16, 8, 4, 2, 1};
  static const int kWw[6]   = {256, 128, 64, 32, 16, 8};
  static const int kOff[6]  = {0, 17965056, 22757376, 24109056, 24526848, 24674304};
  static const int kPer[6]  = {580, 292, 148, 76, 40, 22};
  static const int kCum[7]  = {0, 4640, 6976, 8160, 8768, 9088, 9264};
  int job  = blockIdx.x * 4 + (threadIdx.x >> 6);
  int lane = threadIdx.x & 63;
  int nb = job / NPAD_JOBS;
  if (nb >= nbuf) return;
  int e8 = job - nb * NPAD_JOBS;
  int li = 0;
  #pragma unroll
  for (int i = 1; i < 6; ++i) li = (e8 >= kCum[i]) ? i : li;
  int r = e8 - kCum[li];
  int per = kPer[li];
  int n = r / per;
  int e = r - n * per;
  int H = kHh[li], W = kWw[li], Wp = W + 2;
  int y, x;
  if (e < 2 * Wp) {
    y = (e < Wp) ? 0 : (H + 1);
    x = (e < Wp) ? e : (e - Wp);
  } else {
    int e2 = e - 2 * Wp;
    x = (e2 < H) ? 0 : (W + 1);
    y = 1 + ((e2 < H) ? e2 : (e2 - H));
  }
  size_t base = (size_t)nb * ACT_ELEMS + kOff[li]
              + ((size_t)((n * (H + 2) + y) * Wp + x) << 8) + (lane << 2);
  i32x2 z = {0, 0};
  *(i32x2*)(act + base) = z;
}

// ---- weight prep: [CO][256ci][3][3] f32 -> [CO][t=9][256ci] bf16 ----
__global__ __launch_bounds__(256) void prep_k(const float* __restrict__ w,
                                              __bf16* __restrict__ o, int total)
{
  for (int i = blockIdx.x * 256 + threadIdx.x; i < total; i += gridDim.x * 256) {
    int co = i / 2304;
    int r  = i - co * 2304;
    int t  = r >> 8;
    int ci = r & 255;
    o[i] = (__bf16)w[((co << 8) + ci) * 9 + t];
  }
}

// ---- NCHW f32 feat -> padded NHWC bf16 ----
__global__ __launch_bounds__(256) void convert_k(FPtrs fp, __bf16* __restrict__ act, Desc d)
{
  __shared__ __bf16 T[16 * 264];
  int b  = blockIdx.x;
  int p0 = b << 4;
  int li = 0;
  #pragma unroll
  for (int i = 1; i < 6; ++i) li = (p0 >= d.lv[i].pos_start) ? i : li;
  LevelD L = d.lv[li];
  int lp  = b * 16 - L.pos_start;
  int tid = threadIdx.x;
  int pl = tid & 15;
  int p  = lp + pl;
  int n  = p >> L.logHW;
  int y  = (p >> L.logW) & (L.H - 1);
  int x  = p & (L.W - 1);
  const float* src = fp.f[li];
  size_t base = (size_t)n * ((size_t)L.HW << 8) + (size_t)y * L.W + x;
  int c0 = tid >> 4;
  #pragma unroll
  for (int it = 0; it < 16; ++it) {
    int c = c0 + (it << 4);
    T[pl * 264 + c] = (__bf16)src[base + (size_t)c * L.HW];
  }
  __syncthreads();
  int p2 = tid >> 4;
  int cc = (tid & 15) << 4;
  int pg = lp + p2;
  int n2 = pg >> L.logHW;
  int y2 = (pg >> L.logW) & (L.H - 1);
  int x2 = pg & (L.W - 1);
  __bf16* dst = act + L.act_off +
      ((size_t)((n2 * (L.H + 2) + y2 + 1) * (L.W + 2) + x2 + 1) << 8) + cc;
  i32x4 v0 = *(const i32x4*)&T[p2 * 264 + cc];
  i32x4 v1 = *(const i32x4*)&T[p2 * 264 + cc + 8];
  *(i32x4*)dst       = v0;
  *(i32x4*)(dst + 8) = v1;
}

// ---- mid conv: 256->256, +bias, ReLU ----
// BM=256 co, BN=96 pos, BK=32. 8 waves 4Mx2N, wave 64x48, acc[4][3].
// A direct from global (L2) into regs, prefetched 1 K-tile ahead.
// B via LDS ring-3 (18KB), 1 glds/wave/K-tile, counted vmcnt(5).
__global__ __launch_bounds__(512, 4)
void conv_mid_k(const __bf16* __restrict__ inb, __bf16* __restrict__ outb,
                const __bf16* __restrict__ wT, const float* __restrict__ bias,
                Desc d)
{
  __shared__ __bf16 Bsm[3][3072];   // [96 rows][32 k]
  int b  = xcd_swz(blockIdx.x, 912);
  int li = 0;
  #pragma unroll
  for (int i = 1; i < 6; ++i) li = (b >= d.lv[i].blk_start) ? i : li;
  LevelD L = d.lv[li];
  int p0 = (b - L.blk_start) * 96;
  int tid  = threadIdx.x;              // 0..511
  int lane = tid & 63;
  int wv   = tid >> 6;                 // 0..7
  int wm = wv >> 1, wn = wv & 1;       // 4M x 2N
  int fr = lane & 15, fg = lane >> 4;
  int Wp = L.W + 2;

  // ---- B staging: one 48-lane round (12 rows/wave), source-side swizzle ----
  bool bact = lane < 48;
  const __bf16* gB;
  int ldsB;
  {
    int row = wv * 12 + (lane >> 2);                     // 0..95 (junk masked)
    int sw  = (lane & 3) ^ ((row >> 1) & 3);
    int p  = p0 + row;
    int pc = (p < L.P) ? p : 0;
    int n  = pc >> L.logHW;
    int y  = (pc >> L.logW) & (L.H - 1);
    int x  = pc & (L.W - 1);
    gB = inb + L.act_off + (((n * (L.H + 2) + y) * Wp + x) << 8) + (sw << 3);
    ldsB = (wv * 12) << 5;
  }

  // ---- A fragment pointers: direct global, lane(fr,fg) -> row base+fr, k fg*8
  const __bf16* aG0 = wT + ((wm << 6) + 0  + fr) * 2304 + (fg << 3);
  const __bf16* aG1 = wT + ((wm << 6) + 16 + fr) * 2304 + (fg << 3);
  const __bf16* aG2 = wT + ((wm << 6) + 32 + fr) * 2304 + (fg << 3);
  const __bf16* aG3 = wT + ((wm << 6) + 48 + fr) * 2304 + (fg << 3);

  // ---- B fragment read offsets (elems), swizzled 16B slot ----
  int offB[3];
  #pragma unroll
  for (int nf = 0; nf < 3; ++nf) {
    int row = wn * 48 + (nf << 4) + fr;
    offB[nf] = (row << 5) + ((fg ^ ((fr >> 1) & 3)) << 3);
  }

  auto stageB = [&](int kt, int buf) {
    int t  = kt >> 3;
    int ky = (t >= 6) ? 2 : (t >= 3 ? 1 : 0);
    int kx = t - ky * 3;
    int kb = ((ky * Wp + kx) << 8) + ((kt & 7) << 5);
    if (bact) glds16(gB + kb, &Bsm[buf][ldsB]);
  };

  f32x4 acc[4][3] = {};

  // prologue: B(0),B(1) staged FIRST (oldest VMEM ops), then A(0) into regs.
  stageB(0, 0);
  stageB(1, 1);
  asm volatile("" ::: "memory");       // pin: glds before A loads
  bfrag cA0 = *(const bfrag*)aG0;
  bfrag cA1 = *(const bfrag*)aG1;
  bfrag cA2 = *(const bfrag*)aG2;
  bfrag cA3 = *(const bfrag*)aG3;

  int cur = 0;
  #pragma unroll 1
  for (int kt = 0; kt < 72; ++kt) {
    int sbuf = cur + 2; if (sbuf >= 3) sbuf -= 3;    // (kt+2)%3
    if (kt == 71) { asm volatile("s_waitcnt vmcnt(4)" ::: "memory"); }
    else          { asm volatile("s_waitcnt vmcnt(5)" ::: "memory"); }
    __builtin_amdgcn_s_barrier();
    asm volatile("" ::: "memory");

    bfrag bf3[3];
    #pragma unroll
    for (int nf = 0; nf < 3; ++nf) bf3[nf] = *(const bfrag*)&Bsm[cur][offB[nf]];
    if (kt < 70) stageB(kt + 2, sbuf);

    // prefetch A for kt+1 (compiler tracks the register RAW)
    bfrag pA0, pA1, pA2, pA3;
    if (kt < 71) {
      int ko = (kt + 1) << 5;
      pA0 = *(const bfrag*)(aG0 + ko);
      pA1 = *(const bfrag*)(aG1 + ko);
      pA2 = *(const bfrag*)(aG2 + ko);
      pA3 = *(const bfrag*)(aG3 + ko);
    } else {
      pA0 = cA0; pA1 = cA1; pA2 = cA2; pA3 = cA3;
    }

    __builtin_amdgcn_s_setprio(1);
    #pragma unroll
    for (int nf = 0; nf < 3; ++nf) {
      acc[0][nf] = __builtin_amdgcn_mfma_f32_16x16x32_bf16(cA0, bf3[nf], acc[0][nf], 0, 0, 0);
      acc[1][nf] = __builtin_amdgcn_mfma_f32_16x16x32_bf16(cA1, bf3[nf], acc[1][nf], 0, 0, 0);
      acc[2][nf] = __builtin_amdgcn_mfma_f32_16x16x32_bf16(cA2, bf3[nf], acc[2][nf], 0, 0, 0);
      acc[3][nf] = __builtin_amdgcn_mfma_f32_16x16x32_bf16(cA3, bf3[nf], acc[3][nf], 0, 0, 0);
    }
    __builtin_amdgcn_s_setprio(0);

    cA0 = pA0; cA1 = pA1; cA2 = pA2; cA3 = pA3;
    ++cur; if (cur == 3) cur = 0;
  }

  // epilogue: bias + relu -> bf16 NHWC interior
  #pragma unroll
  for (int nf = 0; nf < 3; ++nf) {
    int pp = p0 + wn * 48 + (nf << 4) + fr;
    if (pp >= L.P) continue;
    int n2 = pp >> L.logHW;
    int y2 = (pp >> L.logW) & (L.H - 1);
    int x2 = pp & (L.W - 1);
    __bf16* ob = outb + L.act_off + (((n2 * (L.H + 2) + y2 + 1) * Wp + x2 + 1) << 8);
    #pragma unroll
    for (int mf = 0; mf < 4; ++mf) {
      int cob = (wm << 6) + (mf << 4) + (fg << 2);
      f32x4 bb = *(const f32x4*)(bias + cob);
      f32x4 v  = acc[mf][nf];
      bf4 ov;
      #pragma unroll
      for (int j = 0; j < 4; ++j) ov[j] = (__bf16)fmaxf(v[j] + bb[j], 0.0f);
      *(bf4*)(ob + cob) = ov;
    }
  }
}

// ---- out conv: 256->Cout (24 reg / 54 cls), +bias, scatter f32 to d_out ----
__global__ __launch_bounds__(256, 3)
void conv_out_k(const __bf16* __restrict__ inb, const __bf16* __restrict__ wT,
                const float* __restrict__ biasO, float* __restrict__ dout,
                Desc d, int Cout, int isCls)
{
  __shared__ __bf16 Asm[2][64 * 32];
  __shared__ __bf16 Bsm[2][128 * 32];
  int b  = xcd_swz(blockIdx.x, 683);
  int li = 0;
  #pragma unroll
  for (int i = 1; i < 6; ++i) li = (b >= d.lv[i].blk_start) ? i : li;
  LevelD L = d.lv[li];
  int p0 = (b - L.blk_start) << 7;
  int tid  = threadIdx.x;
  int lane = tid & 63;
  int wv   = tid >> 6;
  int fr = lane & 15, fg = lane >> 4;
  int Wp = L.W + 2;
  int nmf = (Cout + 15) >> 4;

  int rsub = lane >> 2;
  int slot = lane & 3;
  int sw   = slot ^ ((rsub >> 1) & 3);

  const __bf16* gA0;
  {
    int row = (wv << 4) + rsub;
    int co  = (row < Cout) ? row : 0;
    gA0 = wT + co * 2304 + (sw << 3);
  }
  const __bf16* gB[2];
  #pragma unroll
  for (int j = 0; j < 2; ++j) {
    int row = (j << 6) + (wv << 4) + rsub;
    int p  = p0 + row;
    int pc = (p < L.P) ? p : 0;
    int n = pc >> L.logHW, y = (pc >> L.logW) & (L.H - 1), x = pc & (L.W - 1);
    gB[j] = inb + L.act_off + (((n * (L.H + 2) + y) * Wp + x) << 8) + (sw << 3);
  }
  int dW = (wv << 4) << 5;

  int csw = ((fg ^ ((fr >> 1) & 3)) << 3);
  int offA[4], offB[2];
  #pragma unroll
  for (int mf = 0; mf < 4; ++mf)
    offA[mf] = (((mf << 4) + fr) << 5) + csw;
  #pragma unroll
  for (int nf = 0; nf < 2; ++nf)
    offB[nf] = (((wv << 5) + (nf << 4) + fr) << 5) + csw;

  auto stage = [&](int k, int bb) {
    int t  = k >> 3;
    int ky = (t >= 6) ? 2 : (t >= 3 ? 1 : 0);
    int kx = t - ky * 3;
    int ka = (t << 8) + ((k & 7) << 5);
    int kb = ((ky * Wp + kx) << 8) + ((k & 7) << 5);
    glds16(gA0 + ka, &Asm[bb][dW]);
    glds16(gB[0] + kb, &Bsm[bb][dW]);
    glds16(gB[1] + kb, &Bsm[bb][2048 + dW]);
  };

  f32x4 acc[4][2] = {};

  stage(0, 0);
  #pragma unroll 1
  for (int k = 0; k < 72; ++k) {
    int cur = k & 1;
    __syncthreads();
    if (k < 71) stage(k + 1, cur ^ 1);
    bfrag af[4], bfv[2];
    #pragma unroll
    for (int mf = 0; mf < 4; ++mf)
      if (mf < nmf) af[mf] = *(const bfrag*)&Asm[cur][offA[mf]];
    #pragma unroll
    for (int nf = 0; nf < 2; ++nf)
      bfv[nf] = *(const bfrag*)&Bsm[cur][offB[nf]];
    #pragma unroll
    for (int mf = 0; mf < 4; ++mf)
      if (mf < nmf)
        #pragma unroll
        for (int nf = 0; nf < 2; ++nf)
          acc[mf][nf] = __builtin_amdgcn_mfma_f32_16x16x32_bf16(
              af[mf], bfv[nf], acc[mf][nf], 0, 0, 0);
  }

  #pragma unroll
  for (int nf = 0; nf < 2; ++nf) {
    int pp = p0 + (wv << 5) + (nf << 4) + fr;
    if (pp >= L.P) continue;
    int n2 = pp >> L.logHW;
    int y2 = (pp >> L.logW) & (L.H - 1);
    int x2 = pp & (L.W - 1);
    int sp_off = L.aoff + y2 * L.W + x2;
    #pragma unroll
    for (int mf = 0; mf < 4; ++mf) {
      if (mf < nmf) {
        #pragma unroll
        for (int j = 0; j < 4; ++j) {
          int co = (mf << 4) + (fg << 2) + j;
          if (co < Cout) {
            float val = acc[mf][nf][j] + biasO[co];
            int g   = co / 6;
            int box = co - g * 6;
            size_t idx;
            if (isCls) idx = (size_t)CLS_BASE + ((size_t)n2 * 9 + g) * TOTAL_ANCH
                             + sp_off + box * L.HW;
            else       idx = ((size_t)n2 * 4 + g) * TOTAL_ANCH + sp_off + box * L.HW;
            dout[idx] = val;
          }
        }
      }
    }
  }
}

extern "C" void kernel_launch(void* const* d_in, const int* in_sizes, int n_in,
                              void* d_out, int out_size, void* d_ws, size_t ws_size,
                              hipStream_t stream) {
  if (ws_size < WS_ELEMS * 2) return;  // fail loud: output stays poisoned

  static const int kH[6]      = {32, 16, 8, 4, 2, 1};
  static const int kW[6]      = {256, 128, 64, 32, 16, 8};
  static const int kLogW[6]   = {8, 7, 6, 5, 4, 3};
  static const int kLogHW[6]  = {13, 11, 9, 7, 5, 3};
  static const int kActOff[6] = {0, 17965056, 22757376, 24109056, 24526848, 24674304};
  static const int kAoff[6]   = {0, 49152, 61440, 64512, 65280, 65472};
  static const int kBlkMid[6] = {0, 683, 854, 897, 908, 911};   // BN=96 -> 912
  static const int kBlkOut[6] = {0, 512, 640, 672, 680, 682};   // BN=128 -> 683
  static const int kPosSt[6]  = {0, 65536, 81920, 86016, 87040, 87296};

  FPtrs fp;
  for (int i = 0; i < 6; ++i) fp.f[i] = (const float*)d_in[i];
  const float* reg_w  = (const float*)d_in[6];
  const float* reg_b  = (const float*)d_in[7];
  const float* reg_wo = (const float*)d_in[8];
  const float* reg_bo = (const float*)d_in[9];
  const float* cls_w  = (const float*)d_in[10];
  const float* cls_b  = (const float*)d_in[11];
  const float* cls_wo = (const float*)d_in[12];
  const float* cls_bo = (const float*)d_in[13];
  __bf16* ws = (__bf16*)d_ws;

  Desc dmid, dout_d;
  for (int i = 0; i < 6; ++i) {
    LevelD L;
    L.H = kH[i]; L.W = kW[i]; L.logW = kLogW[i]; L.logHW = kLogHW[i];
    L.HW = kH[i] * kW[i]; L.P = 8 * L.HW;
    L.act_off = kActOff[i]; L.aoff = kAoff[i];
    L.pos_start = kPosSt[i];
    L.blk_start = kBlkMid[i];
    dmid.lv[i] = L;
    L.blk_start = kBlkOut[i];
    dout_d.lv[i] = L;
  }

  bool use3 = ws_size >= (size_t)(ACT0_OFF + 3ull * ACT_ELEMS) * 2ull;
  int nbuf = use3 ? 3 : 2;

  padzero_k<<<(NPAD_JOBS * nbuf + 3) / 4, 256, 0, stream>>>(ws + ACT0_OFF, nbuf);

  prep_k<<<256, 256, 0, stream>>>(reg_w,  ws + WREG_OFF,  1024 * 2304);
  prep_k<<<256, 256, 0, stream>>>(cls_w,  ws + WCLS_OFF,  1024 * 2304);
  prep_k<<<64,  256, 0, stream>>>(reg_wo, ws + WREGO_OFF, 24 * 2304);
  prep_k<<<64,  256, 0, stream>>>(cls_wo, ws + WCLSO_OFF, 54 * 2304);

  if (use3) {
    convert_k<<<5460, 256, 0, stream>>>(fp, ws + ACT2_OFF, dmid);
    for (int head = 0; head < 2; ++head) {
      const __bf16* wT = ws + (head ? WCLS_OFF : WREG_OFF);
      const float*  bb = head ? cls_b : reg_b;
      conv_mid_k<<<912, 512, 0, stream>>>(ws + ACT2_OFF, ws + ACT0_OFF, wT + 0 * 589824, bb + 0,   dmid);
      conv_mid_k<<<912, 512, 0, stream>>>(ws + ACT0_OFF, ws + ACT1_OFF, wT + 1 * 589824, bb + 256, dmid);
      conv_mid_k<<<912, 512, 0, stream>>>(ws + ACT1_OFF, ws + ACT0_OFF, wT + 2 * 589824, bb + 512, dmid);
      conv_mid_k<<<912, 512, 0, stream>>>(ws + ACT0_OFF, ws + ACT1_OFF, wT + 3 * 589824, bb + 768, dmid);
      conv_out_k<<<683, 256, 0, stream>>>(ws + ACT1_OFF,
          ws + (head ? WCLSO_OFF : WREGO_OFF), head ? cls_bo : reg_bo,
          (float*)d_out, dout_d, head ? 54 : 24, head);
    }
  } else {
    for (int head = 0; head < 2; ++head) {
      convert_k<<<5460, 256, 0, stream>>>(fp, ws + ACT0_OFF, dmid);
      const __bf16* wT = ws + (head ? WCLS_OFF : WREG_OFF);
      const float*  bb = head ? cls_b : reg_b;
      conv_mid_k<<<912, 512, 0, stream>>>(ws + ACT0_OFF, ws + ACT1_OFF, wT + 0 * 589824, bb + 0,   dmid);
      conv_mid_k<<<912, 512, 0, stream>>>(ws + ACT1_OFF, ws + ACT0_OFF, wT + 1 * 589824, bb + 256, dmid);
      conv_mid_k<<<912, 512, 0, stream>>>(ws + ACT0_OFF, ws + ACT1_OFF, wT + 2 * 589824, bb + 512, dmid);
      conv_mid_k<<<912, 512, 0, stream>>>(ws + ACT1_OFF, ws + ACT0_OFF, wT + 3 * 589824, bb + 768, dmid);
      conv_out_k<<<683, 256, 0, stream>>>(ws + ACT0_OFF,
          ws + (head ? WCLSO_OFF : WREGO_OFF), head ? cls_bo : reg_bo,
          (float*)d_out, dout_d, head ? 54 : 24, head);
    }
  }
}

// Round 19
// 1187.121 us; speedup vs baseline: 2.1874x; 2.1874x over previous
//
#include <hip/hip_runtime.h>
#include <hip/hip_bf16.h>

// RetinaNet head on MI355X. R19 = exact revert to R15 (measured best:
// 1189.7us). R18's A-from-global regressed 2.3x (scattered L2 loads
// latency-exposed under counted vmcnt). This is the plateau configuration:
// BM=256 x BN=96 (grid 912, 89% packing at 2 blk/CU), 512thr/8 waves
// (4Mx2N, wave 64x48, acc 48 regs), ring-3 LDS 66KB -> 16 waves/CU,
// one phase/K-tile {7 ds_read | stage kt+2 (3 glds/wave) | barrier |
// lgkm0 | setprio + 12 MFMA}, counted vmcnt(3), XCD swizzle, halo-only
// zeroing, convert-once.

typedef float  f32x4 __attribute__((ext_vector_type(4)));
typedef int    i32x4 __attribute__((ext_vector_type(4)));
typedef int    i32x2 __attribute__((ext_vector_type(2)));
typedef __bf16 bfrag __attribute__((ext_vector_type(8)));
typedef __bf16 bf4   __attribute__((ext_vector_type(4)));

struct LevelD {
  int H, W, logW, logHW, P, HW, act_off, aoff, blk_start, pos_start;
};
struct Desc  { LevelD lv[6]; };
struct FPtrs { const float* f[6]; };

#define ACT_ELEMS  24735744
#define WREG_OFF   0
#define WCLS_OFF   2359296
#define WREGO_OFF  4718592
#define WCLSO_OFF  4773888
#define ACT0_OFF   4898304
#define ACT1_OFF   29634048
#define ACT2_OFF   54369792
#define WS_ELEMS   54369792ull
#define TOTAL_ANCH 65520
#define CLS_BASE   2096640
#define NPAD_JOBS  9264

__device__ __forceinline__ void glds16(const __bf16* g, __bf16* l) {
  __builtin_amdgcn_global_load_lds(
      (const __attribute__((address_space(1))) void*)g,
      (__attribute__((address_space(3))) void*)l, 16, 0, 0);
}

// bijective XCD-chunk swizzle (m204)
__device__ __forceinline__ int xcd_swz(int b, int nwg) {
  int xcd = b & 7;
  int q = nwg >> 3, r = nwg & 7;
  int base = (xcd < r) ? xcd * (q + 1) : r * (q + 1) + (xcd - r) * q;
  return base + (b >> 3);
}

// ---- halo zeroing ----
__global__ __launch_bounds__(256) void padzero_k(__bf16* __restrict__ act, int nbuf)
{
  static const int kHh[6]   = {32, 16, 8, 4, 2, 1};
  static const int kWw[6]   = {256, 128, 64, 32, 16, 8};
  static const int kOff[6]  = {0, 17965056, 22757376, 24109056, 24526848, 24674304};
  static const int kPer[6]  = {580, 292, 148, 76, 40, 22};
  static const int kCum[7]  = {0, 4640, 6976, 8160, 8768, 9088, 9264};
  int job  = blockIdx.x * 4 + (threadIdx.x >> 6);
  int lane = threadIdx.x & 63;
  int nb = job / NPAD_JOBS;
  if (nb >= nbuf) return;
  int e8 = job - nb * NPAD_JOBS;
  int li = 0;
  #pragma unroll
  for (int i = 1; i < 6; ++i) li = (e8 >= kCum[i]) ? i : li;
  int r = e8 - kCum[li];
  int per = kPer[li];
  int n = r / per;
  int e = r - n * per;
  int H = kHh[li], W = kWw[li], Wp = W + 2;
  int y, x;
  if (e < 2 * Wp) {
    y = (e < Wp) ? 0 : (H + 1);
    x = (e < Wp) ? e : (e - Wp);
  } else {
    int e2 = e - 2 * Wp;
    x = (e2 < H) ? 0 : (W + 1);
    y = 1 + ((e2 < H) ? e2 : (e2 - H));
  }
  size_t base = (size_t)nb * ACT_ELEMS + kOff[li]
              + ((size_t)((n * (H + 2) + y) * Wp + x) << 8) + (lane << 2);
  i32x2 z = {0, 0};
  *(i32x2*)(act + base) = z;
}

// ---- weight prep: [CO][256ci][3][3] f32 -> [CO][t=9][256ci] bf16 ----
__global__ __launch_bounds__(256) void prep_k(const float* __restrict__ w,
                                              __bf16* __restrict__ o, int total)
{
  for (int i = blockIdx.x * 256 + threadIdx.x; i < total; i += gridDim.x * 256) {
    int co = i / 2304;
    int r  = i - co * 2304;
    int t  = r >> 8;
    int ci = r & 255;
    o[i] = (__bf16)w[((co << 8) + ci) * 9 + t];
  }
}

// ---- NCHW f32 feat -> padded NHWC bf16 ----
__global__ __launch_bounds__(256) void convert_k(FPtrs fp, __bf16* __restrict__ act, Desc d)
{
  __shared__ __bf16 T[16 * 264];
  int b  = blockIdx.x;
  int p0 = b << 4;
  int li = 0;
  #pragma unroll
  for (int i = 1; i < 6; ++i) li = (p0 >= d.lv[i].pos_start) ? i : li;
  LevelD L = d.lv[li];
  int lp  = b * 16 - L.pos_start;
  int tid = threadIdx.x;
  int pl = tid & 15;
  int p  = lp + pl;
  int n  = p >> L.logHW;
  int y  = (p >> L.logW) & (L.H - 1);
  int x  = p & (L.W - 1);
  const float* src = fp.f[li];
  size_t base = (size_t)n * ((size_t)L.HW << 8) + (size_t)y * L.W + x;
  int c0 = tid >> 4;
  #pragma unroll
  for (int it = 0; it < 16; ++it) {
    int c = c0 + (it << 4);
    T[pl * 264 + c] = (__bf16)src[base + (size_t)c * L.HW];
  }
  __syncthreads();
  int p2 = tid >> 4;
  int cc = (tid & 15) << 4;
  int pg = lp + p2;
  int n2 = pg >> L.logHW;
  int y2 = (pg >> L.logW) & (L.H - 1);
  int x2 = pg & (L.W - 1);
  __bf16* dst = act + L.act_off +
      ((size_t)((n2 * (L.H + 2) + y2 + 1) * (L.W + 2) + x2 + 1) << 8) + cc;
  i32x4 v0 = *(const i32x4*)&T[p2 * 264 + cc];
  i32x4 v1 = *(const i32x4*)&T[p2 * 264 + cc + 8];
  *(i32x4*)dst       = v0;
  *(i32x4*)(dst + 8) = v1;
}

// ---- mid conv: 256->256, +bias, ReLU ----
// BM=256 co, BN=96 pos, BK=32. 8 waves 4Mx2N, wave 64x48, acc[4][3].
// Ring-3 LDS (66KB, 2 blocks/CU). One phase/K-tile, counted vmcnt(3).
__global__ __launch_bounds__(512, 4)
void conv_mid_k(const __bf16* __restrict__ inb, __bf16* __restrict__ outb,
                const __bf16* __restrict__ wT, const float* __restrict__ bias,
                Desc d)
{
  __shared__ __bf16 Asm[3][8192];   // [256 rows][32 k], 64B rows
  __shared__ __bf16 Bsm[3][3072];   // [96 rows][32 k]
  int b  = xcd_swz(blockIdx.x, 912);
  int li = 0;
  #pragma unroll
  for (int i = 1; i < 6; ++i) li = (b >= d.lv[i].blk_start) ? i : li;
  LevelD L = d.lv[li];
  int p0 = (b - L.blk_start) * 96;
  int tid  = threadIdx.x;              // 0..511
  int lane = tid & 63;
  int wv   = tid >> 6;                 // 0..7
  int wm = wv >> 1, wn = wv & 1;       // 4M x 2N
  int fr = lane & 15, fg = lane >> 4;
  int Wp = L.W + 2;

  // ---- staging: A = 2 full-wave rounds; B = one 48-lane round (12 rows/wave)
  const __bf16* gA[2];
  int ldsA[2];
  #pragma unroll
  for (int r = 0; r < 2; ++r) {
    int row = (r << 7) + (wv << 4) + (lane >> 2);        // 0..255
    int sw  = (lane & 3) ^ ((row >> 1) & 3);
    gA[r] = wT + row * 2304 + (sw << 3);
    ldsA[r] = ((r << 7) + (wv << 4)) << 5;
  }
  bool bact = lane < 48;
  const __bf16* gB;
  int ldsB;
  {
    int row = wv * 12 + (lane >> 2);                     // 0..95 (junk masked)
    int sw  = (lane & 3) ^ ((row >> 1) & 3);
    int p  = p0 + row;
    int pc = (p < L.P) ? p : 0;
    int n  = pc >> L.logHW;
    int y  = (pc >> L.logW) & (L.H - 1);
    int x  = pc & (L.W - 1);
    gB = inb + L.act_off + (((n * (L.H + 2) + y) * Wp + x) << 8) + (sw << 3);
    ldsB = (wv * 12) << 5;
  }

  // ---- fragment read offsets (elems), swizzled 16B slot ----
  int offA[4], offB[3];
  #pragma unroll
  for (int mf = 0; mf < 4; ++mf) {
    int row = (wm << 6) + (mf << 4) + fr;
    offA[mf] = (row << 5) + ((fg ^ ((fr >> 1) & 3)) << 3);
  }
  #pragma unroll
  for (int nf = 0; nf < 3; ++nf) {
    int row = wn * 48 + (nf << 4) + fr;
    offB[nf] = (row << 5) + ((fg ^ ((fr >> 1) & 3)) << 3);
  }

  auto stage = [&](int kt, int buf) {
    int ko = ((kt >> 3) << 8) + ((kt & 7) << 5);
    glds16(gA[0] + ko, &Asm[buf][ldsA[0]]);
    glds16(gA[1] + ko, &Asm[buf][ldsA[1]]);
    int t  = kt >> 3;
    int ky = (t >= 6) ? 2 : (t >= 3 ? 1 : 0);
    int kx = t - ky * 3;
    int kb = ((ky * Wp + kx) << 8) + ((kt & 7) << 5);
    if (bact) glds16(gB + kb, &Bsm[buf][ldsB]);
  };

  f32x4 acc[4][3] = {};

  // prologue: stage kt=0 -> buf0, kt=1 -> buf1 (3 loads/wave each)
  stage(0, 0);
  stage(1, 1);

  int cur = 0;
  #pragma unroll 1
  for (int kt = 0; kt < 72; ++kt) {
    int sbuf = cur + 2; if (sbuf >= 3) sbuf -= 3;    // (kt+2)%3
    if (kt == 71) { asm volatile("s_waitcnt vmcnt(0)" ::: "memory"); }
    else          { asm volatile("s_waitcnt vmcnt(3)" ::: "memory"); }
    __builtin_amdgcn_s_barrier();
    asm volatile("" ::: "memory");

    bfrag bf3[3], a0, a1, a2, a3;
    #pragma unroll
    for (int nf = 0; nf < 3; ++nf) bf3[nf] = *(const bfrag*)&Bsm[cur][offB[nf]];
    a0 = *(const bfrag*)&Asm[cur][offA[0]];
    a1 = *(const bfrag*)&Asm[cur][offA[1]];
    a2 = *(const bfrag*)&Asm[cur][offA[2]];
    a3 = *(const bfrag*)&Asm[cur][offA[3]];
    if (kt < 70) stage(kt + 2, sbuf);
    asm volatile("s_waitcnt lgkmcnt(0)" ::: "memory");
    __builtin_amdgcn_sched_barrier(0);
    __builtin_amdgcn_s_setprio(1);
    #pragma unroll
    for (int nf = 0; nf < 3; ++nf) {
      acc[0][nf] = __builtin_amdgcn_mfma_f32_16x16x32_bf16(a0, bf3[nf], acc[0][nf], 0, 0, 0);
      acc[1][nf] = __builtin_amdgcn_mfma_f32_16x16x32_bf16(a1, bf3[nf], acc[1][nf], 0, 0, 0);
      acc[2][nf] = __builtin_amdgcn_mfma_f32_16x16x32_bf16(a2, bf3[nf], acc[2][nf], 0, 0, 0);
      acc[3][nf] = __builtin_amdgcn_mfma_f32_16x16x32_bf16(a3, bf3[nf], acc[3][nf], 0, 0, 0);
    }
    __builtin_amdgcn_s_setprio(0);

    ++cur; if (cur == 3) cur = 0;
  }

  // epilogue: bias + relu -> bf16 NHWC interior
  #pragma unroll
  for (int nf = 0; nf < 3; ++nf) {
    int pp = p0 + wn * 48 + (nf << 4) + fr;
    if (pp >= L.P) continue;
    int n2 = pp >> L.logHW;
    int y2 = (pp >> L.logW) & (L.H - 1);
    int x2 = pp & (L.W - 1);
    __bf16* ob = outb + L.act_off + (((n2 * (L.H + 2) + y2 + 1) * Wp + x2 + 1) << 8);
    #pragma unroll
    for (int mf = 0; mf < 4; ++mf) {
      int cob = (wm << 6) + (mf << 4) + (fg << 2);
      f32x4 bb = *(const f32x4*)(bias + cob);
      f32x4 v  = acc[mf][nf];
      bf4 ov;
      #pragma unroll
      for (int j = 0; j < 4; ++j) ov[j] = (__bf16)fmaxf(v[j] + bb[j], 0.0f);
      *(bf4*)(ob + cob) = ov;
    }
  }
}

// ---- out conv: 256->Cout (24 reg / 54 cls), +bias, scatter f32 to d_out ----
__global__ __launch_bounds__(256, 3)
void conv_out_k(const __bf16* __restrict__ inb, const __bf16* __restrict__ wT,
                const float* __restrict__ biasO, float* __restrict__ dout,
                Desc d, int Cout, int isCls)
{
  __shared__ __bf16 Asm[2][64 * 32];
  __shared__ __bf16 Bsm[2][128 * 32];
  int b  = xcd_swz(blockIdx.x, 683);
  int li = 0;
  #pragma unroll
  for (int i = 1; i < 6; ++i) li = (b >= d.lv[i].blk_start) ? i : li;
  LevelD L = d.lv[li];
  int p0 = (b - L.blk_start) << 7;
  int tid  = threadIdx.x;
  int lane = tid & 63;
  int wv   = tid >> 6;
  int fr = lane & 15, fg = lane >> 4;
  int Wp = L.W + 2;
  int nmf = (Cout + 15) >> 4;

  int rsub = lane >> 2;
  int slot = lane & 3;
  int sw   = slot ^ ((rsub >> 1) & 3);

  const __bf16* gA0;
  {
    int row = (wv << 4) + rsub;
    int co  = (row < Cout) ? row : 0;
    gA0 = wT + co * 2304 + (sw << 3);
  }
  const __bf16* gB[2];
  #pragma unroll
  for (int j = 0; j < 2; ++j) {
    int row = (j << 6) + (wv << 4) + rsub;
    int p  = p0 + row;
    int pc = (p < L.P) ? p : 0;
    int n = pc >> L.logHW, y = (pc >> L.logW) & (L.H - 1), x = pc & (L.W - 1);
    gB[j] = inb + L.act_off + (((n * (L.H + 2) + y) * Wp + x) << 8) + (sw << 3);
  }
  int dW = (wv << 4) << 5;

  int csw = ((fg ^ ((fr >> 1) & 3)) << 3);
  int offA[4], offB[2];
  #pragma unroll
  for (int mf = 0; mf < 4; ++mf)
    offA[mf] = (((mf << 4) + fr) << 5) + csw;
  #pragma unroll
  for (int nf = 0; nf < 2; ++nf)
    offB[nf] = (((wv << 5) + (nf << 4) + fr) << 5) + csw;

  auto stage = [&](int k, int bb) {
    int t  = k >> 3;
    int ky = (t >= 6) ? 2 : (t >= 3 ? 1 : 0);
    int kx = t - ky * 3;
    int ka = (t << 8) + ((k & 7) << 5);
    int kb = ((ky * Wp + kx) << 8) + ((k & 7) << 5);
    glds16(gA0 + ka, &Asm[bb][dW]);
    glds16(gB[0] + kb, &Bsm[bb][dW]);
    glds16(gB[1] + kb, &Bsm[bb][2048 + dW]);
  };

  f32x4 acc[4][2] = {};

  stage(0, 0);
  #pragma unroll 1
  for (int k = 0; k < 72; ++k) {
    int cur = k & 1;
    __syncthreads();
    if (k < 71) stage(k + 1, cur ^ 1);
    bfrag af[4], bfv[2];
    #pragma unroll
    for (int mf = 0; mf < 4; ++mf)
      if (mf < nmf) af[mf] = *(const bfrag*)&Asm[cur][offA[mf]];
    #pragma unroll
    for (int nf = 0; nf < 2; ++nf)
      bfv[nf] = *(const bfrag*)&Bsm[cur][offB[nf]];
    #pragma unroll
    for (int mf = 0; mf < 4; ++mf)
      if (mf < nmf)
        #pragma unroll
        for (int nf = 0; nf < 2; ++nf)
          acc[mf][nf] = __builtin_amdgcn_mfma_f32_16x16x32_bf16(
              af[mf], bfv[nf], acc[mf][nf], 0, 0, 0);
  }

  #pragma unroll
  for (int nf = 0; nf < 2; ++nf) {
    int pp = p0 + (wv << 5) + (nf << 4) + fr;
    if (pp >= L.P) continue;
    int n2 = pp >> L.logHW;
    int y2 = (pp >> L.logW) & (L.H - 1);
    int x2 = pp & (L.W - 1);
    int sp_off = L.aoff + y2 * L.W + x2;
    #pragma unroll
    for (int mf = 0; mf < 4; ++mf) {
      if (mf < nmf) {
        #pragma unroll
        for (int j = 0; j < 4; ++j) {
          int co = (mf << 4) + (fg << 2) + j;
          if (co < Cout) {
            float val = acc[mf][nf][j] + biasO[co];
            int g   = co / 6;
            int box = co - g * 6;
            size_t idx;
            if (isCls) idx = (size_t)CLS_BASE + ((size_t)n2 * 9 + g) * TOTAL_ANCH
                             + sp_off + box * L.HW;
            else       idx = ((size_t)n2 * 4 + g) * TOTAL_ANCH + sp_off + box * L.HW;
            dout[idx] = val;
          }
        }
      }
    }
  }
}

extern "C" void kernel_launch(void* const* d_in, const int* in_sizes, int n_in,
                              void* d_out, int out_size, void* d_ws, size_t ws_size,
                              hipStream_t stream) {
  if (ws_size < WS_ELEMS * 2) return;  // fail loud: output stays poisoned

  static const int kH[6]      = {32, 16, 8, 4, 2, 1};
  static const int kW[6]      = {256, 128, 64, 32, 16, 8};
  static const int kLogW[6]   = {8, 7, 6, 5, 4, 3};
  static const int kLogHW[6]  = {13, 11, 9, 7, 5, 3};
  static const int kActOff[6] = {0, 17965056, 22757376, 24109056, 24526848, 24674304};
  static const int kAoff[6]   = {0, 49152, 61440, 64512, 65280, 65472};
  static const int kBlkMid[6] = {0, 683, 854, 897, 908, 911};   // BN=96 -> 912
  static const int kBlkOut[6] = {0, 512, 640, 672, 680, 682};   // BN=128 -> 683
  static const int kPosSt[6]  = {0, 65536, 81920, 86016, 87040, 87296};

  FPtrs fp;
  for (int i = 0; i < 6; ++i) fp.f[i] = (const float*)d_in[i];
  const float* reg_w  = (const float*)d_in[6];
  const float* reg_b  = (const float*)d_in[7];
  const float* reg_wo = (const float*)d_in[8];
  const float* reg_bo = (const float*)d_in[9];
  const float* cls_w  = (const float*)d_in[10];
  const float* cls_b  = (const float*)d_in[11];
  const float* cls_wo = (const float*)d_in[12];
  const float* cls_bo = (const float*)d_in[13];
  __bf16* ws = (__bf16*)d_ws;

  Desc dmid, dout_d;
  for (int i = 0; i < 6; ++i) {
    LevelD L;
    L.H = kH[i]; L.W = kW[i]; L.logW = kLogW[i]; L.logHW = kLogHW[i];
    L.HW = kH[i] * kW[i]; L.P = 8 * L.HW;
    L.act_off = kActOff[i]; L.aoff = kAoff[i];
    L.pos_start = kPosSt[i];
    L.blk_start = kBlkMid[i];
    dmid.lv[i] = L;
    L.blk_start = kBlkOut[i];
    dout_d.lv[i] = L;
  }

  bool use3 = ws_size >= (size_t)(ACT0_OFF + 3ull * ACT_ELEMS) * 2ull;
  int nbuf = use3 ? 3 : 2;

  padzero_k<<<(NPAD_JOBS * nbuf + 3) / 4, 256, 0, stream>>>(ws + ACT0_OFF, nbuf);

  prep_k<<<256, 256, 0, stream>>>(reg_w,  ws + WREG_OFF,  1024 * 2304);
  prep_k<<<256, 256, 0, stream>>>(cls_w,  ws + WCLS_OFF,  1024 * 2304);
  prep_k<<<64,  256, 0, stream>>>(reg_wo, ws + WREGO_OFF, 24 * 2304);
  prep_k<<<64,  256, 0, stream>>>(cls_wo, ws + WCLSO_OFF, 54 * 2304);

  if (use3) {
    convert_k<<<5460, 256, 0, stream>>>(fp, ws + ACT2_OFF, dmid);
    for (int head = 0; head < 2; ++head) {
      const __bf16* wT = ws + (head ? WCLS_OFF : WREG_OFF);
      const float*  bb = head ? cls_b : reg_b;
      conv_mid_k<<<912, 512, 0, stream>>>(ws + ACT2_OFF, ws + ACT0_OFF, wT + 0 * 589824, bb + 0,   dmid);
      conv_mid_k<<<912, 512, 0, stream>>>(ws + ACT0_OFF, ws + ACT1_OFF, wT + 1 * 589824, bb + 256, dmid);
      conv_mid_k<<<912, 512, 0, stream>>>(ws + ACT1_OFF, ws + ACT0_OFF, wT + 2 * 589824, bb + 512, dmid);
      conv_mid_k<<<912, 512, 0, stream>>>(ws + ACT0_OFF, ws + ACT1_OFF, wT + 3 * 589824, bb + 768, dmid);
      conv_out_k<<<683, 256, 0, stream>>>(ws + ACT1_OFF,
          ws + (head ? WCLSO_OFF : WREGO_OFF), head ? cls_bo : reg_bo,
          (float*)d_out, dout_d, head ? 54 : 24, head);
    }
  } else {
    for (int head = 0; head < 2; ++head) {
      convert_k<<<5460, 256, 0, stream>>>(fp, ws + ACT0_OFF, dmid);
      const __bf16* wT = ws + (head ? WCLS_OFF : WREG_OFF);
      const float*  bb = head ? cls_b : reg_b;
      conv_mid_k<<<912, 512, 0, stream>>>(ws + ACT0_OFF, ws + ACT1_OFF, wT + 0 * 589824, bb + 0,   dmid);
      conv_mid_k<<<912, 512, 0, stream>>>(ws + ACT1_OFF, ws + ACT0_OFF, wT + 1 * 589824, bb + 256, dmid);
      conv_mid_k<<<912, 512, 0, stream>>>(ws + ACT0_OFF, ws + ACT1_OFF, wT + 2 * 589824, bb + 512, dmid);
      conv_mid_k<<<912, 512, 0, stream>>>(ws + ACT1_OFF, ws + ACT0_OFF, wT + 3 * 589824, bb + 768, dmid);
      conv_out_k<<<683, 256, 0, stream>>>(ws + ACT0_OFF,
          ws + (head ? WCLSO_OFF : WREGO_OFF), head ? cls_bo : reg_bo,
          (float*)d_out, dout_d, head ? 54 : 24, head);
    }
  }
}